// Round 5
// baseline (10092.374 us; speedup 1.0000x reference)
//
#include <hip/hip_runtime.h>
#include <math.h>

#define L 8
#define H 1024
#define NH 16
#define KVH 4
#define HD 64
#define INTER 2816
#define VOCAB 32000
#define CTX 2048
#define EPS 1e-5f
#define NCHUNK 32          // CTX / 64
#define PART_STRIDE 68     // m, l, o[64], pad
#define NBLK 1024          // exactly 4 blocks/CU on 256 CUs — co-residency guaranteed

__device__ inline float wave_reduce_sum(float v) {
    #pragma unroll
    for (int off = 32; off > 0; off >>= 1)
        v += __shfl_xor(v, off, 64);
    return v;
}

__device__ inline float wave_reduce_max(float v) {
    #pragma unroll
    for (int off = 32; off > 0; off >>= 1)
        v = fmaxf(v, __shfl_xor(v, off, 64));
    return v;
}

// Monotonic grid barrier: all NBLK blocks co-resident (guaranteed by launch_bounds+LDS).
// Release: threadfence + device-scope atomic add. Acquire: device-scope load + threadfence
// (agent-scope acquire invalidates L1 and cross-XCD-stale L2 lines; same fence pattern as
// the flash-decode semaphore that passed absmax=0.0 in rounds 0-2).
__device__ inline void gsync(unsigned* bar, unsigned* phase) {
    __syncthreads();
    if (threadIdx.x == 0) {
        unsigned ph = ++(*phase);
        __threadfence();
        __hip_atomic_fetch_add(bar, 1u, __ATOMIC_RELEASE, __HIP_MEMORY_SCOPE_AGENT);
        unsigned target = ph * (unsigned)NBLK;
        while (__hip_atomic_load(bar, __ATOMIC_ACQUIRE, __HIP_MEMORY_SCOPE_AGENT) < target)
            __builtin_amdgcn_s_sleep(8);
        __threadfence();
    }
    __syncthreads();
}

// zero the barrier counter + attention semaphores (workspace is poisoned between calls)
__global__ void init_kernel(unsigned* __restrict__ bar, int* __restrict__ cnt) {
    int t = threadIdx.x;
    if (t == 0) *bar = 0u;
    if (t < 16) cnt[t] = 0;
}

__global__ __launch_bounds__(256, 4) void mega_kernel(
    const float* __restrict__ embed,  const float* __restrict__ q_w,
    const float* __restrict__ k_w,    const float* __restrict__ v_w,
    const float* __restrict__ o_w,    const float* __restrict__ gate_w,
    const float* __restrict__ up_w,   const float* __restrict__ down_w,
    const float* __restrict__ ln1_w,  const float* __restrict__ ln2_w,
    const float* __restrict__ norm_w, const float* __restrict__ lm_head,
    const float* __restrict__ kv_cache, const float* __restrict__ cos_c,
    const float* __restrict__ sin_c,  const int* __restrict__ input_ids,
    const int* __restrict__ position_ids,
    float* __restrict__ h, float* __restrict__ h2, float* __restrict__ qb,
    float* __restrict__ kb, float* __restrict__ vb, float* __restrict__ aob,
    float* __restrict__ tb, float* __restrict__ part, int* __restrict__ cnt,
    unsigned* __restrict__ bar, unsigned long long* __restrict__ blockmax,
    float* __restrict__ out) {
    const int bid = blockIdx.x;
    const int t = threadIdx.x;
    const int wv = t >> 6, lane = t & 63;
    const int gw = bid * 4 + wv;            // global wave id 0..4095
    unsigned phase = 0;
    __shared__ float smem[8704];            // 34.8 KB, aliased per phase
    __shared__ int s_last;
    __shared__ unsigned long long s_best[4];
    float* xs   = smem;                     // [1024] rms'd activation
    float* red4 = smem + 1024;              // [4]
    const int pos = position_ids[0];

    // ---- embed ----
    if (bid == 0) {
        const float4* e4 = (const float4*)(embed + (size_t)input_ids[0] * H);
        ((float4*)h)[t] = e4[t];
    }
    gsync(bar, &phase);

    for (int l = 0; l < L; ++l) {
        const float* qw  = q_w    + (size_t)l * H * H;
        const float* kw  = k_w    + (size_t)l * (KVH * HD) * H;
        const float* vw  = v_w    + (size_t)l * (KVH * HD) * H;
        const float* ow  = o_w    + (size_t)l * H * H;
        const float* gtw = gate_w + (size_t)l * INTER * H;
        const float* uw  = up_w   + (size_t)l * INTER * H;
        const float* dw  = down_w + (size_t)l * H * INTER;
        const float* Kc  = kv_cache + (size_t)l * KVH * CTX * HD;
        const float* Vc  = kv_cache + (size_t)(L + l) * KVH * CTX * HD;

        // ---- phase 1: rms(h,ln1) + qkv matvec (1536 rows, wave/row) ----
        if (bid < 384) {
            const float* lnw = ln1_w + (size_t)l * H;
            float4 hv = ((const float4*)h)[t];
            float ss = hv.x*hv.x + hv.y*hv.y + hv.z*hv.z + hv.w*hv.w;
            ss = wave_reduce_sum(ss);
            if (lane == 0) red4[wv] = ss;
            __syncthreads();
            float rs = rsqrtf((red4[0]+red4[1]+red4[2]+red4[3]) * (1.f/(float)H) + EPS);
            float4 wvv = ((const float4*)lnw)[t];
            float4 xv;
            xv.x = hv.x*rs*wvv.x; xv.y = hv.y*rs*wvv.y;
            xv.z = hv.z*rs*wvv.z; xv.w = hv.w*rs*wvv.w;
            ((float4*)xs)[t] = xv;
            __syncthreads();
            int row = bid * 4 + wv;
            const float* W; float* outp; int r;
            if (row < H)            { W = qw; outp = qb; r = row; }
            else if (row < H + 256) { W = kw; outp = kb; r = row - H; }
            else                    { W = vw; outp = vb; r = row - H - 256; }
            const float4* W4 = (const float4*)(W + (size_t)r * H);
            const float4* x4 = (const float4*)xs;
            float acc = 0.f;
            #pragma unroll
            for (int i = lane; i < H/4; i += 64) {
                float4 a = W4[i], b = x4[i];
                acc += a.x*b.x + a.y*b.y + a.z*b.z + a.w*b.w;
            }
            acc = wave_reduce_sum(acc);
            if (lane == 0) outp[r] = acc;
        }
        gsync(bar, &phase);

        // ---- phase 2: flash-decode attention (RoPE fused, semaphore combine) ----
        if (bid < NH * NCHUNK) {
            int hh = bid >> 5, c = bid & 31;
            int p0 = c * 64;
            if (p0 <= pos) {
                float* Kt  = smem;          // [64*65] transposed, stride 65
                float* Vt  = smem + 4160;   // [64*64]
                float* qs  = smem + 8256;   // [64]
                float* e_s = smem + 8320;   // [64]
                float* red = smem + 8384;   // [256]
                int kvh = hh >> 2;
                const float* K = Kc + (size_t)kvh * CTX * HD;
                const float* V = Vc + (size_t)kvh * CTX * HD;
                const float* cr = cos_c + (size_t)pos * HD;
                const float* sr = sin_c + (size_t)pos * HD;
                if (t < 64) {
                    float a = qb[hh * HD + t];
                    float b = qb[hh * HD + (t ^ 32)];
                    float sgn = (t < 32) ? -1.f : 1.f;
                    qs[t] = a * cr[t] + sgn * b * sr[t];
                }
                #pragma unroll
                for (int j = t; j < 1024; j += 256) {
                    int p = j >> 4, dq = j & 15;
                    int pg = p0 + p;
                    float4 kv4, vv4;
                    if (pg > pos) {
                        kv4 = make_float4(0.f, 0.f, 0.f, 0.f); vv4 = kv4;
                    } else if (pg == pos) {
                        float4 a  = *(const float4*)(kb + kvh * HD + dq * 4);
                        float4 b  = *(const float4*)(kb + kvh * HD + (dq ^ 8) * 4);
                        float4 c4 = *(const float4*)(cr + dq * 4);
                        float4 s4 = *(const float4*)(sr + dq * 4);
                        float sgn = (dq < 8) ? -1.f : 1.f;
                        kv4.x = a.x*c4.x + sgn*b.x*s4.x;
                        kv4.y = a.y*c4.y + sgn*b.y*s4.y;
                        kv4.z = a.z*c4.z + sgn*b.z*s4.z;
                        kv4.w = a.w*c4.w + sgn*b.w*s4.w;
                        vv4 = *(const float4*)(vb + kvh * HD + dq * 4);
                    } else {
                        kv4 = *(const float4*)(K + (size_t)pg * HD + dq * 4);
                        vv4 = *(const float4*)(V + (size_t)pg * HD + dq * 4);
                    }
                    Kt[(4 * dq + 0) * 65 + p] = kv4.x;
                    Kt[(4 * dq + 1) * 65 + p] = kv4.y;
                    Kt[(4 * dq + 2) * 65 + p] = kv4.z;
                    Kt[(4 * dq + 3) * 65 + p] = kv4.w;
                    *(float4*)(Vt + p * 64 + dq * 4) = vv4;
                }
                __syncthreads();
                if (t < 64) {
                    int pg = p0 + t;
                    float acc = 0.f;
                    #pragma unroll 8
                    for (int i = 0; i < 64; ++i)
                        acc += qs[i] * Kt[i * 65 + t];
                    float s = (pg > pos) ? -INFINITY : acc * 0.125f;
                    float m = wave_reduce_max(s);
                    float e = (pg > pos) ? 0.f : expf(s - m);
                    float lsum = wave_reduce_sum(e);
                    e_s[t] = e;
                    if (t == 0) {
                        float* pb = part + (size_t)(hh * NCHUNK + c) * PART_STRIDE;
                        pb[0] = m; pb[1] = lsum;
                    }
                }
                __syncthreads();
                int g = t >> 6, d = t & 63;
                float acc = 0.f;
                #pragma unroll
                for (int pp = 0; pp < 16; ++pp) {
                    int p = g * 16 + pp;
                    acc += e_s[p] * Vt[p * 64 + d];
                }
                red[t] = acc;
                __syncthreads();
                if (t < 64) {
                    float o = red[t] + red[64 + t] + red[128 + t] + red[192 + t];
                    part[(size_t)(hh * NCHUNK + c) * PART_STRIDE + 2 + t] = o;
                }
                __syncthreads();
                int ncc = (pos >> 6) + 1;
                if (t == 0) {
                    __threadfence();
                    s_last = (atomicAdd(&cnt[hh], 1) == ncc - 1);
                }
                __syncthreads();
                if (s_last) {
                    __threadfence();
                    if (t < 64) {
                        const volatile float* pa = part + (size_t)hh * NCHUNK * PART_STRIDE;
                        float M = -INFINITY;
                        for (int cc = 0; cc < ncc; ++cc)
                            M = fmaxf(M, pa[(size_t)cc * PART_STRIDE]);
                        float Lsum = 0.f, oacc = 0.f;
                        for (int cc = 0; cc < ncc; ++cc) {
                            const volatile float* pb = pa + (size_t)cc * PART_STRIDE;
                            float w = expf(pb[0] - M);
                            Lsum += w * pb[1];
                            oacc += w * pb[2 + t];
                        }
                        aob[hh * HD + t] = oacc / Lsum;
                    }
                    if (t == 0) cnt[hh] = 0;   // ready for next layer
                }
            }
        }
        gsync(bar, &phase);

        // ---- phase 3: o-proj + residual (1024 rows, wave/row) ----
        if (bid < 256) {
            int row = gw;
            const float4* W4 = (const float4*)(ow + (size_t)row * H);
            const float4* x4 = (const float4*)aob;
            float acc = 0.f;
            #pragma unroll
            for (int i = lane; i < H/4; i += 64) {
                float4 a = W4[i], b = x4[i];
                acc += a.x*b.x + a.y*b.y + a.z*b.z + a.w*b.w;
            }
            acc = wave_reduce_sum(acc);
            if (lane == 0) h2[row] = h[row] + acc;
        }
        gsync(bar, &phase);

        // ---- phase 4: rms(h2,ln2) + gate/up (2816 rows, wave/row) ----
        if (bid < 704) {
            const float* lnw = ln2_w + (size_t)l * H;
            float4 hv = ((const float4*)h2)[t];
            float ss = hv.x*hv.x + hv.y*hv.y + hv.z*hv.z + hv.w*hv.w;
            ss = wave_reduce_sum(ss);
            if (lane == 0) red4[wv] = ss;
            __syncthreads();
            float rs = rsqrtf((red4[0]+red4[1]+red4[2]+red4[3]) * (1.f/(float)H) + EPS);
            float4 wvv = ((const float4*)lnw)[t];
            float4 xv;
            xv.x = hv.x*rs*wvv.x; xv.y = hv.y*rs*wvv.y;
            xv.z = hv.z*rs*wvv.z; xv.w = hv.w*rs*wvv.w;
            ((float4*)xs)[t] = xv;
            __syncthreads();
            int row = bid * 4 + wv;
            const float4* g4 = (const float4*)(gtw + (size_t)row * H);
            const float4* u4 = (const float4*)(uw + (size_t)row * H);
            const float4* x4 = (const float4*)xs;
            float ag = 0.f, au = 0.f;
            #pragma unroll
            for (int i = lane; i < H/4; i += 64) {
                float4 b = x4[i];
                float4 a = g4[i];
                ag += a.x*b.x + a.y*b.y + a.z*b.z + a.w*b.w;
                float4 c4 = u4[i];
                au += c4.x*b.x + c4.y*b.y + c4.z*b.z + c4.w*b.w;
            }
            ag = wave_reduce_sum(ag);
            au = wave_reduce_sum(au);
            if (lane == 0) {
                float sg = ag / (1.f + expf(-ag));
                tb[row] = sg * au;
            }
        }
        gsync(bar, &phase);

        // ---- phase 5: down-proj + residual (1024 rows, wave/row, K=INTER) ----
        if (bid < 256) {
            int row = gw;
            const float4* W4 = (const float4*)(dw + (size_t)row * INTER);
            const float4* x4 = (const float4*)tb;
            float acc = 0.f;
            #pragma unroll
            for (int i = lane; i < INTER/4; i += 64) {
                float4 a = W4[i], b = x4[i];
                acc += a.x*b.x + a.y*b.y + a.z*b.z + a.w*b.w;
            }
            acc = wave_reduce_sum(acc);
            if (lane == 0) h[row] = h2[row] + acc;
        }
        gsync(bar, &phase);
    }

    // ---- final: rms(h,norm) + lm_head + per-block argmax ----
    {
        float4 hv = ((const float4*)h)[t];
        float ss = hv.x*hv.x + hv.y*hv.y + hv.z*hv.z + hv.w*hv.w;
        ss = wave_reduce_sum(ss);
        if (lane == 0) red4[wv] = ss;
        __syncthreads();
        float rs = rsqrtf((red4[0]+red4[1]+red4[2]+red4[3]) * (1.f/(float)H) + EPS);
        float4 wvv = ((const float4*)norm_w)[t];
        float4 xv;
        xv.x = hv.x*rs*wvv.x; xv.y = hv.y*rs*wvv.y;
        xv.z = hv.z*rs*wvv.z; xv.w = hv.w*rs*wvv.w;
        ((float4*)xs)[t] = xv;
        __syncthreads();
        unsigned long long best = 0ULL;
        for (int r = gw; r < VOCAB; r += 4 * NBLK) {
            const float4* W4 = (const float4*)(lm_head + (size_t)r * H);
            const float4* x4 = (const float4*)xs;
            float acc = 0.f;
            #pragma unroll
            for (int i = lane; i < H/4; i += 64) {
                float4 a = W4[i], b = x4[i];
                acc += a.x*b.x + a.y*b.y + a.z*b.z + a.w*b.w;
            }
            acc = wave_reduce_sum(acc);              // all lanes hold the sum
            unsigned ub = __float_as_uint(acc);
            unsigned enc = (ub & 0x80000000u) ? ~ub : (ub | 0x80000000u);
            unsigned long long e =
                ((unsigned long long)enc << 32) | (unsigned long long)(~(unsigned)r);
            if (e > best) best = e;                  // strict '>': first (smallest r) max wins
        }
        if (lane == 0) s_best[wv] = best;
        __syncthreads();
        if (t == 0) {
            unsigned long long b = s_best[0];
            #pragma unroll
            for (int i = 1; i < 4; ++i)
                if (s_best[i] > b) b = s_best[i];
            blockmax[bid] = b;
        }
    }
    gsync(bar, &phase);
    if (bid == 0) {
        unsigned long long v = 0ULL;
        for (int i = t; i < NBLK; i += 256) {
            unsigned long long u = blockmax[i];
            if (u > v) v = u;
        }
        unsigned long long* sred = (unsigned long long*)smem;
        sred[t] = v;
        __syncthreads();
        for (int off = 128; off > 0; off >>= 1) {
            if (t < off && sred[t + off] > sred[t]) sred[t] = sred[t + off];
            __syncthreads();
        }
        if (t == 0) {
            unsigned long long r = sred[0];
            unsigned enc = (unsigned)(r >> 32);
            unsigned bits = (enc & 0x80000000u) ? (enc & 0x7FFFFFFFu) : ~enc;
            int idx = (int)(~(unsigned)(r & 0xFFFFFFFFu));
            out[0] = (float)idx;
            out[1] = __uint_as_float(bits);
        }
    }
}

extern "C" void kernel_launch(void* const* d_in, const int* in_sizes, int n_in,
                              void* d_out, int out_size, void* d_ws, size_t ws_size,
                              hipStream_t stream) {
    const float* embed   = (const float*)d_in[0];
    const float* q_w     = (const float*)d_in[1];
    const float* k_w     = (const float*)d_in[2];
    const float* v_w     = (const float*)d_in[3];
    const float* o_w     = (const float*)d_in[4];
    const float* gate_w  = (const float*)d_in[5];
    const float* up_w    = (const float*)d_in[6];
    const float* down_w  = (const float*)d_in[7];
    const float* ln1_w   = (const float*)d_in[8];
    const float* ln2_w   = (const float*)d_in[9];
    const float* norm_w  = (const float*)d_in[10];
    const float* lm_head = (const float*)d_in[11];
    const float* kv_cache= (const float*)d_in[12];
    const float* cos_c   = (const float*)d_in[13];
    const float* sin_c   = (const float*)d_in[14];
    const int* input_ids    = (const int*)d_in[17];
    const int* position_ids = (const int*)d_in[18];

    float* ws = (float*)d_ws;
    float* h      = ws;            // 1024
    float* h2     = ws + 1024;     // 1024
    float* qb     = ws + 2048;     // 1024
    float* kb     = ws + 3072;     // 256
    float* vb     = ws + 3328;     // 256
    float* aob    = ws + 3584;     // 1024
    float* tb     = ws + 4608;     // 2816
    float* part   = ws + 7424;     // 34816 → ends 42240
    int*   cnt    = (int*)(ws + 42240);       // 16 attn semaphores
    unsigned* bar = (unsigned*)(ws + 42256);  // grid-barrier counter
    unsigned long long* blockmax = (unsigned long long*)(ws + 42264); // 1024 u64 (8B-aligned)

    init_kernel<<<1, 64, 0, stream>>>(bar, cnt);
    mega_kernel<<<NBLK, 256, 0, stream>>>(
        embed, q_w, k_w, v_w, o_w, gate_w, up_w, down_w, ln1_w, ln2_w,
        norm_w, lm_head, kv_cache, cos_c, sin_c, input_ids, position_ids,
        h, h2, qb, kb, vb, aob, tb, part, cnt, bar, blockmax, (float*)d_out);
}